// Round 1
// baseline (578.712 us; speedup 1.0000x reference)
//
#include <hip/hip_runtime.h>
#include <math.h>

#define BB 16
#define CC 256
#define HH 128
#define WW 128
#define HWSZ 16384
#define RR 16

__global__ void pool_kernel(const float* __restrict__ x,
                            float* __restrict__ avg_out,
                            float* __restrict__ max_out) {
    int bc = blockIdx.x;  // 0..4095
    const float4* xp = reinterpret_cast<const float4*>(x + (size_t)bc * HWSZ);
    int tid = threadIdx.x;
    float s = 0.f, m = -INFINITY;
#pragma unroll
    for (int it = 0; it < 16; ++it) {
        float4 v = xp[tid + it * 256];
        s += v.x + v.y + v.z + v.w;
        m = fmaxf(m, fmaxf(fmaxf(v.x, v.y), fmaxf(v.z, v.w)));
    }
    for (int o = 32; o > 0; o >>= 1) {
        s += __shfl_down(s, o);
        m = fmaxf(m, __shfl_down(m, o));
    }
    __shared__ float ss[4], sm[4];
    int wave = tid >> 6;
    if ((tid & 63) == 0) { ss[wave] = s; sm[wave] = m; }
    __syncthreads();
    if (tid == 0) {
        float st = ss[0] + ss[1] + ss[2] + ss[3];
        float mt = fmaxf(fmaxf(sm[0], sm[1]), fmaxf(sm[2], sm[3]));
        avg_out[bc] = st * (1.0f / HWSZ);
        max_out[bc] = mt;
    }
}

__global__ void mlp_kernel(const float* __restrict__ avg, const float* __restrict__ mx,
                           const float* __restrict__ w1, const float* __restrict__ b1,
                           const float* __restrict__ w2, const float* __restrict__ b2,
                           float* __restrict__ wch) {
    int b = blockIdx.x;
    int tid = threadIdx.x;
    __shared__ float s_in[2][CC];
    __shared__ float s_h[2][RR];
    s_in[0][tid] = avg[b * CC + tid];
    s_in[1][tid] = mx[b * CC + tid];
    __syncthreads();
    // 32 (which,row) pairs x 8 lanes each
    int pair = tid >> 3;   // 0..31
    int lane8 = tid & 7;
    int which = pair >> 4; // 0..1
    int row = pair & 15;
    float acc = 0.f;
#pragma unroll
    for (int c0 = 0; c0 < CC; c0 += 8)
        acc += s_in[which][c0 + lane8] * w1[row * CC + c0 + lane8];
    acc += __shfl_down(acc, 4);
    acc += __shfl_down(acc, 2);
    acc += __shfl_down(acc, 1);
    if (lane8 == 0) s_h[which][row] = fmaxf(acc + b1[row], 0.f);
    __syncthreads();
    float o = 2.f * b2[tid];
#pragma unroll
    for (int r = 0; r < RR; ++r)
        o += w2[tid * RR + r] * (s_h[0][r] + s_h[1][r]);
    wch[b * CC + tid] = 1.f / (1.f + expf(-o));
}

__global__ void spatial_stats_kernel(const float* __restrict__ x,
                                     const float* __restrict__ wch,
                                     float* __restrict__ cat) {
    int blk = blockIdx.x;  // 256 blocks
    int b = blk >> 4;
    int chunk = blk & 15;
    int tid = threadIdx.x;
    __shared__ float s_w[CC];
    s_w[tid] = wch[b * CC + tid];
    __syncthreads();
    int p4 = chunk * 256 + tid;  // float4 index within the plane, [0,4096)
    const float4* xp = reinterpret_cast<const float4*>(x) + (size_t)b * CC * (HWSZ / 4) + p4;
    float sx = 0.f, sy = 0.f, sz = 0.f, sw = 0.f;
    float mx_ = -INFINITY, my_ = -INFINITY, mz_ = -INFINITY, mw_ = -INFINITY;
#pragma unroll 4
    for (int c = 0; c < CC; ++c) {
        float4 v = xp[(size_t)c * (HWSZ / 4)];
        float w = s_w[c];
        float vx = v.x * w, vy = v.y * w, vz = v.z * w, vw = v.w * w;
        sx += vx; sy += vy; sz += vz; sw += vw;
        mx_ = fmaxf(mx_, vx); my_ = fmaxf(my_, vy);
        mz_ = fmaxf(mz_, vz); mw_ = fmaxf(mw_, vw);
    }
    const float inv = 1.f / CC;
    float4 m = {mx_, my_, mz_, mw_};
    float4 a = {sx * inv, sy * inv, sz * inv, sw * inv};
    float4* catp = reinterpret_cast<float4*>(cat);
    catp[((size_t)b * 2 + 0) * (HWSZ / 4) + p4] = m;  // maxmap (channel 0)
    catp[((size_t)b * 2 + 1) * (HWSZ / 4) + p4] = a;  // avgmap (channel 1)
}

__global__ __launch_bounds__(256) void dsa_kernel(
    const float* __restrict__ cat,
    const float* __restrict__ off_w, const float* __restrict__ off_b,
    const float* __restrict__ dc_w, const float* __restrict__ dc_b,
    const float* __restrict__ bn_gamma, const float* __restrict__ bn_beta,
    const float* __restrict__ bn_mean, const float* __restrict__ bn_var,
    float* __restrict__ wsout) {
    __shared__ float s_offw[324], s_offb[18], s_dcw[18];
    __shared__ float s_bnscale, s_bnshift, s_dcb;
    int tid = threadIdx.x;
    for (int idx = tid; idx < 324; idx += 256) s_offw[idx] = off_w[idx];
    if (tid < 18) { s_offb[tid] = off_b[tid]; s_dcw[tid] = dc_w[tid]; }
    if (tid == 0) {
        float inv = bn_gamma[0] * rsqrtf(bn_var[0] + 1e-5f);
        s_bnscale = inv;
        s_bnshift = bn_beta[0] - bn_mean[0] * inv;
        s_dcb = dc_b[0];
    }
    __syncthreads();
    int blk = blockIdx.x;  // 1024 blocks
    int b = blk >> 6;
    int p = (blk & 63) * 256 + tid;
    int i = p >> 7, j = p & 127;
    const float* c0 = cat + ((size_t)b * 2 + 0) * HWSZ;
    const float* c1 = cat + ((size_t)b * 2 + 1) * HWSZ;
    // 3x3 zero-padded stencil of both channels
    float n0[9], n1[9];
#pragma unroll
    for (int ky = 0; ky < 3; ++ky)
#pragma unroll
        for (int kx = 0; kx < 3; ++kx) {
            int yy = i + ky - 1, xx = j + kx - 1;
            bool v = (yy >= 0) && (yy < HH) && (xx >= 0) && (xx < WW);
            int idx = yy * WW + xx;
            n0[ky * 3 + kx] = v ? c0[idx] : 0.f;
            n1[ky * 3 + kx] = v ? c1[idx] : 0.f;
        }
    // offsets conv: 18 outputs
    float off[18];
#pragma unroll
    for (int k = 0; k < 18; ++k) {
        float acc = s_offb[k];
#pragma unroll
        for (int t = 0; t < 9; ++t)
            acc += n0[t] * s_offw[(k * 2 + 0) * 9 + t] + n1[t] * s_offw[(k * 2 + 1) * 9 + t];
        off[k] = acc;
    }
    // deformable 3x3 conv (2->1) with bilinear sampling
    float d = s_dcb;
#pragma unroll
    for (int k = 0; k < 9; ++k) {
        float py = (float)i + (float)(k / 3 - 1) + off[2 * k];
        float px = (float)j + (float)(k % 3 - 1) + off[2 * k + 1];
        float y0f = floorf(py), x0f = floorf(px);
        float wy = py - y0f, wx = px - x0f;
        int y0 = (int)y0f, x0 = (int)x0f;
        float w00 = (1.f - wy) * (1.f - wx), w01 = (1.f - wy) * wx;
        float w10 = wy * (1.f - wx), w11 = wy * wx;
        float s0 = 0.f, s1 = 0.f;
#pragma unroll
        for (int cy = 0; cy < 2; ++cy)
#pragma unroll
            for (int cx = 0; cx < 2; ++cx) {
                int yi = y0 + cy, xi = x0 + cx;
                bool v = (yi >= 0) && (yi < HH) && (xi >= 0) && (xi < WW);
                float ww = (cy == 0) ? (cx == 0 ? w00 : w01) : (cx == 0 ? w10 : w11);
                if (v) {
                    int idx = yi * WW + xi;
                    s0 += c0[idx] * ww;
                    s1 += c1[idx] * ww;
                }
            }
        d += s0 * s_dcw[k] + s1 * s_dcw[9 + k];
    }
    d = d * s_bnscale + s_bnshift;
    wsout[(size_t)b * HWSZ + p] = 1.f / (1.f + expf(-d));
}

__global__ void final_kernel(const float* __restrict__ x, const float* __restrict__ wch,
                             const float* __restrict__ wsmap, float* __restrict__ out) {
    size_t t = (size_t)blockIdx.x * 256 + threadIdx.x;  // float4 index
    int plane = (int)(t >> 12);  // 4096 float4 per (b,c) plane
    int b = plane >> 8;
    int c = plane & 255;
    int p4 = (int)(t & 4095);
    float4 xv = reinterpret_cast<const float4*>(x)[t];
    float4 wv = reinterpret_cast<const float4*>(wsmap)[(size_t)b * 4096 + p4];
    float wc = wch[b * 256 + c];
    float4 o;
    o.x = xv.x * (1.f + wc * wv.x);
    o.y = xv.y * (1.f + wc * wv.y);
    o.z = xv.z * (1.f + wc * wv.z);
    o.w = xv.w * (1.f + wc * wv.w);
    reinterpret_cast<float4*>(out)[t] = o;
}

extern "C" void kernel_launch(void* const* d_in, const int* in_sizes, int n_in,
                              void* d_out, int out_size, void* d_ws, size_t ws_size,
                              hipStream_t stream) {
    const float* x       = (const float*)d_in[0];
    const float* w1      = (const float*)d_in[1];
    const float* b1      = (const float*)d_in[2];
    const float* w2      = (const float*)d_in[3];
    const float* b2      = (const float*)d_in[4];
    const float* off_w   = (const float*)d_in[5];
    const float* off_b   = (const float*)d_in[6];
    const float* dc_w    = (const float*)d_in[7];
    const float* dc_b    = (const float*)d_in[8];
    const float* bn_gamma= (const float*)d_in[9];
    const float* bn_beta = (const float*)d_in[10];
    const float* bn_mean = (const float*)d_in[11];
    const float* bn_var  = (const float*)d_in[12];

    float* wsf   = (float*)d_ws;
    float* avg   = wsf;                      // 4096
    float* mx    = wsf + 4096;               // 4096
    float* wch   = wsf + 8192;               // 4096
    float* cat   = wsf + 12288;              // 16*2*16384 = 524288
    float* wsmap = wsf + 12288 + 524288;     // 16*16384  = 262144
    float* out   = (float*)d_out;

    pool_kernel<<<BB * CC, 256, 0, stream>>>(x, avg, mx);
    mlp_kernel<<<BB, 256, 0, stream>>>(avg, mx, w1, b1, w2, b2, wch);
    spatial_stats_kernel<<<256, 256, 0, stream>>>(x, wch, cat);
    dsa_kernel<<<1024, 256, 0, stream>>>(cat, off_w, off_b, dc_w, dc_b,
                                         bn_gamma, bn_beta, bn_mean, bn_var, wsmap);
    final_kernel<<<65536, 256, 0, stream>>>(x, wch, wsmap, out);
}

// Round 3
// 568.864 us; speedup vs baseline: 1.0173x; 1.0173x over previous
//
#include <hip/hip_runtime.h>
#include <math.h>

#define BB 16
#define CC 256
#define HH 128
#define WW 128
#define HWSZ 16384
#define RR 16

__global__ void pool_kernel(const float* __restrict__ x,
                            float* __restrict__ avg_out,
                            float* __restrict__ max_out) {
    int bc = blockIdx.x;  // 0..4095
    const float4* xp = reinterpret_cast<const float4*>(x + (size_t)bc * HWSZ);
    int tid = threadIdx.x;
    float s = 0.f, m = -INFINITY;
#pragma unroll
    for (int it = 0; it < 16; ++it) {
        float4 v = xp[tid + it * 256];
        s += v.x + v.y + v.z + v.w;
        m = fmaxf(m, fmaxf(fmaxf(v.x, v.y), fmaxf(v.z, v.w)));
    }
    for (int o = 32; o > 0; o >>= 1) {
        s += __shfl_down(s, o);
        m = fmaxf(m, __shfl_down(m, o));
    }
    __shared__ float ss[4], sm[4];
    int wave = tid >> 6;
    if ((tid & 63) == 0) { ss[wave] = s; sm[wave] = m; }
    __syncthreads();
    if (tid == 0) {
        float st = ss[0] + ss[1] + ss[2] + ss[3];
        float mt = fmaxf(fmaxf(sm[0], sm[1]), fmaxf(sm[2], sm[3]));
        avg_out[bc] = st * (1.0f / HWSZ);
        max_out[bc] = mt;
    }
}

// Fused: per-block channel-MLP (redundant per chunk, tiny) + per-pixel channel stats.
// Grid: 16 b * 64 chunks = 1024 blocks. Block: 256 threads = 64 pixel4 x 4 channel-splits.
__global__ __launch_bounds__(256) void spatial_stats_kernel(
    const float* __restrict__ x,
    const float* __restrict__ avg, const float* __restrict__ mxin,
    const float* __restrict__ w1, const float* __restrict__ b1,
    const float* __restrict__ w2, const float* __restrict__ b2,
    float* __restrict__ cat) {
    int blk = blockIdx.x;
    int b = blk >> 6;
    int chunk = blk & 63;
    int tid = threadIdx.x;
    __shared__ float s_in[2][CC];
    __shared__ float s_h[2][RR];
    __shared__ float s_w[CC];
    __shared__ float s_red[4][8][64];  // [csplit][elem][pixel]
    s_in[0][tid] = avg[b * CC + tid];
    s_in[1][tid] = mxin[b * CC + tid];
    __syncthreads();
    // ---- MLP ----
    {
        int pair = tid >> 3;   // 0..31
        int lane8 = tid & 7;
        int which = pair >> 4; // 0..1
        int row = pair & 15;
        float acc = 0.f;
#pragma unroll
        for (int c0 = 0; c0 < CC; c0 += 8)
            acc += s_in[which][c0 + lane8] * w1[row * CC + c0 + lane8];
        acc += __shfl_down(acc, 4);
        acc += __shfl_down(acc, 2);
        acc += __shfl_down(acc, 1);
        if (lane8 == 0) s_h[which][row] = fmaxf(acc + b1[row], 0.f);
    }
    __syncthreads();
    {
        float o = 2.f * b2[tid];
#pragma unroll
        for (int r = 0; r < RR; ++r)
            o += w2[tid * RR + r] * (s_h[0][r] + s_h[1][r]);
        s_w[tid] = 1.f / (1.f + expf(-o));
    }
    __syncthreads();
    // ---- per-pixel channel reduce, 4-way channel split ----
    int pp = tid & 63;       // pixel4 within chunk (lane id)
    int csplit = tid >> 6;   // wave id: channels [csplit*64, csplit*64+64)
    int p4 = chunk * 64 + pp;
    const float4* xp = reinterpret_cast<const float4*>(x)
                       + (size_t)b * CC * (HWSZ / 4)
                       + (size_t)csplit * 64 * (HWSZ / 4) + p4;
    float sx = 0.f, sy = 0.f, sz = 0.f, sw = 0.f;
    float mx_ = -INFINITY, my_ = -INFINITY, mz_ = -INFINITY, mw_ = -INFINITY;
    for (int cb = 0; cb < 8; ++cb) {
        float4 v[8];
#pragma unroll
        for (int u = 0; u < 8; ++u)
            v[u] = xp[(size_t)(cb * 8 + u) * (HWSZ / 4)];
#pragma unroll
        for (int u = 0; u < 8; ++u) {
            float w = s_w[csplit * 64 + cb * 8 + u];
            float vx = v[u].x * w, vy = v[u].y * w, vz = v[u].z * w, vw = v[u].w * w;
            sx += vx; sy += vy; sz += vz; sw += vw;
            mx_ = fmaxf(mx_, vx); my_ = fmaxf(my_, vy);
            mz_ = fmaxf(mz_, vz); mw_ = fmaxf(mw_, vw);
        }
    }
    s_red[csplit][0][pp] = sx; s_red[csplit][1][pp] = sy;
    s_red[csplit][2][pp] = sz; s_red[csplit][3][pp] = sw;
    s_red[csplit][4][pp] = mx_; s_red[csplit][5][pp] = my_;
    s_red[csplit][6][pp] = mz_; s_red[csplit][7][pp] = mw_;
    __syncthreads();
    if (csplit == 0) {
        float fs[4], fm[4];
#pragma unroll
        for (int e = 0; e < 4; ++e)
            fs[e] = s_red[0][e][pp] + s_red[1][e][pp] + s_red[2][e][pp] + s_red[3][e][pp];
#pragma unroll
        for (int e = 0; e < 4; ++e)
            fm[e] = fmaxf(fmaxf(s_red[0][e + 4][pp], s_red[1][e + 4][pp]),
                          fmaxf(s_red[2][e + 4][pp], s_red[3][e + 4][pp]));
        const float inv = 1.f / CC;
        float4 m = {fm[0], fm[1], fm[2], fm[3]};
        float4 a = {fs[0] * inv, fs[1] * inv, fs[2] * inv, fs[3] * inv};
        float4* catp = reinterpret_cast<float4*>(cat);
        catp[((size_t)b * 2 + 0) * (HWSZ / 4) + p4] = m;  // maxmap
        catp[((size_t)b * 2 + 1) * (HWSZ / 4) + p4] = a;  // avgmap
    }
}

__global__ __launch_bounds__(256) void dsa_kernel(
    const float* __restrict__ cat,
    const float* __restrict__ off_w, const float* __restrict__ off_b,
    const float* __restrict__ dc_w, const float* __restrict__ dc_b,
    const float* __restrict__ bn_gamma, const float* __restrict__ bn_beta,
    const float* __restrict__ bn_mean, const float* __restrict__ bn_var,
    float* __restrict__ wsout) {
    __shared__ float s_offw[324], s_offb[18], s_dcw[18];
    __shared__ float s_bnscale, s_bnshift, s_dcb;
    int tid = threadIdx.x;
    for (int idx = tid; idx < 324; idx += 256) s_offw[idx] = off_w[idx];
    if (tid < 18) { s_offb[tid] = off_b[tid]; s_dcw[tid] = dc_w[tid]; }
    if (tid == 0) {
        float inv = bn_gamma[0] * rsqrtf(bn_var[0] + 1e-5f);
        s_bnscale = inv;
        s_bnshift = bn_beta[0] - bn_mean[0] * inv;
        s_dcb = dc_b[0];
    }
    __syncthreads();
    int blk = blockIdx.x;  // 1024 blocks
    int b = blk >> 6;
    int p = (blk & 63) * 256 + tid;
    int i = p >> 7, j = p & 127;
    const float* c0 = cat + ((size_t)b * 2 + 0) * HWSZ;
    const float* c1 = cat + ((size_t)b * 2 + 1) * HWSZ;
    float n0[9], n1[9];
#pragma unroll
    for (int ky = 0; ky < 3; ++ky)
#pragma unroll
        for (int kx = 0; kx < 3; ++kx) {
            int yy = i + ky - 1, xx = j + kx - 1;
            float v = ((yy >= 0) & (yy < HH) & (xx >= 0) & (xx < WW)) ? 1.f : 0.f;
            int yc = min(max(yy, 0), HH - 1), xc = min(max(xx, 0), WW - 1);
            int idx = yc * WW + xc;
            n0[ky * 3 + kx] = c0[idx] * v;
            n1[ky * 3 + kx] = c1[idx] * v;
        }
    float off[18];
#pragma unroll
    for (int k = 0; k < 18; ++k) {
        float acc = s_offb[k];
#pragma unroll
        for (int t = 0; t < 9; ++t)
            acc += n0[t] * s_offw[(k * 2 + 0) * 9 + t] + n1[t] * s_offw[(k * 2 + 1) * 9 + t];
        off[k] = acc;
    }
    float d = s_dcb;
#pragma unroll
    for (int k = 0; k < 9; ++k) {
        float py = (float)i + (float)(k / 3 - 1) + off[2 * k];
        float px = (float)j + (float)(k % 3 - 1) + off[2 * k + 1];
        float y0f = floorf(py), x0f = floorf(px);
        float wy = py - y0f, wx = px - x0f;
        int y0 = (int)y0f, x0 = (int)x0f;
        float s0 = 0.f, s1 = 0.f;
#pragma unroll
        for (int cy = 0; cy < 2; ++cy)
#pragma unroll
            for (int cx = 0; cx < 2; ++cx) {
                int yi = y0 + cy, xi = x0 + cx;
                float valid = ((yi >= 0) & (yi < HH) & (xi >= 0) & (xi < WW)) ? 1.f : 0.f;
                float wwy = cy ? wy : (1.f - wy);
                float wwx = cx ? wx : (1.f - wx);
                float ww = wwy * wwx * valid;
                int yc = min(max(yi, 0), HH - 1), xc = min(max(xi, 0), WW - 1);
                int idx = yc * WW + xc;
                s0 += c0[idx] * ww;
                s1 += c1[idx] * ww;
            }
        d += s0 * s_dcw[k] + s1 * s_dcw[9 + k];
    }
    d = d * s_bnscale + s_bnshift;
    wsout[(size_t)b * HWSZ + p] = 1.f / (1.f + expf(-d));
}

__global__ void final_kernel(const float* __restrict__ x, const float* __restrict__ wch,
                             const float* __restrict__ wsmap, float* __restrict__ out) {
    size_t t = (size_t)blockIdx.x * 256 + threadIdx.x;  // float4 index
    int plane = (int)(t >> 12);
    int b = plane >> 8;
    int c = plane & 255;
    int p4 = (int)(t & 4095);
    float4 xv = reinterpret_cast<const float4*>(x)[t];
    float4 wv = reinterpret_cast<const float4*>(wsmap)[(size_t)b * 4096 + p4];
    float wc = wch[b * 256 + c];
    float4 o;
    o.x = xv.x * (1.f + wc * wv.x);
    o.y = xv.y * (1.f + wc * wv.y);
    o.z = xv.z * (1.f + wc * wv.z);
    o.w = xv.w * (1.f + wc * wv.w);
    reinterpret_cast<float4*>(out)[t] = o;
}

// Tiny kernel to materialize wch for final_kernel (same math as the fused MLP).
__global__ void mlp_kernel(const float* __restrict__ avg, const float* __restrict__ mx,
                           const float* __restrict__ w1, const float* __restrict__ b1,
                           const float* __restrict__ w2, const float* __restrict__ b2,
                           float* __restrict__ wch) {
    int b = blockIdx.x;
    int tid = threadIdx.x;
    __shared__ float s_in[2][CC];
    __shared__ float s_h[2][RR];
    s_in[0][tid] = avg[b * CC + tid];
    s_in[1][tid] = mx[b * CC + tid];
    __syncthreads();
    int pair = tid >> 3;
    int lane8 = tid & 7;
    int which = pair >> 4;
    int row = pair & 15;
    float acc = 0.f;
#pragma unroll
    for (int c0 = 0; c0 < CC; c0 += 8)
        acc += s_in[which][c0 + lane8] * w1[row * CC + c0 + lane8];
    acc += __shfl_down(acc, 4);
    acc += __shfl_down(acc, 2);
    acc += __shfl_down(acc, 1);
    if (lane8 == 0) s_h[which][row] = fmaxf(acc + b1[row], 0.f);
    __syncthreads();
    float o = 2.f * b2[tid];
#pragma unroll
    for (int r = 0; r < RR; ++r)
        o += w2[tid * RR + r] * (s_h[0][r] + s_h[1][r]);
    wch[b * CC + tid] = 1.f / (1.f + expf(-o));
}

extern "C" void kernel_launch(void* const* d_in, const int* in_sizes, int n_in,
                              void* d_out, int out_size, void* d_ws, size_t ws_size,
                              hipStream_t stream) {
    const float* x       = (const float*)d_in[0];
    const float* w1      = (const float*)d_in[1];
    const float* b1      = (const float*)d_in[2];
    const float* w2      = (const float*)d_in[3];
    const float* b2      = (const float*)d_in[4];
    const float* off_w   = (const float*)d_in[5];
    const float* off_b   = (const float*)d_in[6];
    const float* dc_w    = (const float*)d_in[7];
    const float* dc_b    = (const float*)d_in[8];
    const float* bn_gamma= (const float*)d_in[9];
    const float* bn_beta = (const float*)d_in[10];
    const float* bn_mean = (const float*)d_in[11];
    const float* bn_var  = (const float*)d_in[12];

    float* wsf   = (float*)d_ws;
    float* avg   = wsf;                      // 4096
    float* mx    = wsf + 4096;               // 4096
    float* wch   = wsf + 8192;               // 4096
    float* cat   = wsf + 12288;              // 16*2*16384
    float* wsmap = wsf + 12288 + 524288;     // 16*16384
    float* out   = (float*)d_out;

    pool_kernel<<<BB * CC, 256, 0, stream>>>(x, avg, mx);
    mlp_kernel<<<BB, 256, 0, stream>>>(avg, mx, w1, b1, w2, b2, wch);
    spatial_stats_kernel<<<1024, 256, 0, stream>>>(x, avg, mx, w1, b1, w2, b2, cat);
    dsa_kernel<<<1024, 256, 0, stream>>>(cat, off_w, off_b, dc_w, dc_b,
                                         bn_gamma, bn_beta, bn_mean, bn_var, wsmap);
    final_kernel<<<65536, 256, 0, stream>>>(x, wch, wsmap, out);
}